// Round 17
// baseline (69.039 us; speedup 1.0000x reference)
//
#include <hip/hip_runtime.h>
#include <math.h>

#define NN 8192
#define DD 512
#define CC 1000
#define CP 1024   // padded C
#define CPD (CP*DD)

typedef __attribute__((ext_vector_type(8))) short short8;     // bf16x8 MFMA frag
typedef __attribute__((ext_vector_type(4))) float f32x4;
typedef __attribute__((ext_vector_type(4))) unsigned short us4;
typedef __attribute__((ext_vector_type(8))) unsigned short us8;

__device__ __forceinline__ float bf2f(unsigned short u){
  union{unsigned int i; float f;} v; v.i = ((unsigned int)u)<<16; return v.f;
}
__device__ __forceinline__ unsigned short f2bf(float f){
  union{float f; unsigned int i;} v; v.f = f;
  unsigned int r = v.i + 0x7FFF + ((v.i>>16)&1);   // RNE
  return (unsigned short)(r>>16);
}
__device__ __forceinline__ float waveRedSum(float v){
  #pragma unroll
  for(int o=32;o;o>>=1) v += __shfl_xor(v,o,64);
  return v;
}
__device__ __forceinline__ float waveRedMax(float v){
  #pragma unroll
  for(int o=32;o;o>>=1) v = fmaxf(v,__shfl_xor(v,o,64));
  return v;
}
__device__ __forceinline__ void gload_lds16(const void* g, void* l){
  __builtin_amdgcn_global_load_lds((const __attribute__((address_space(1))) void*)g,
                                   (__attribute__((address_space(3))) void*)l, 16, 0, 0);
}

// ---- K1: merged prep. Blocks interleaved 4 castF : 1 softmaxT (256 groups of 5).
//      softmaxT handles 32-row i-stripes so PbT writes are 64B/lane contiguous.
__global__ __launch_bounds__(256) void k_prep(const float* __restrict__ F,
                                              const float* __restrict__ L,
                                              unsigned short* __restrict__ FbT,
                                              unsigned short* __restrict__ Fb,
                                              float* __restrict__ gpart,
                                              unsigned short* __restrict__ PbT,
                                              float* __restrict__ out){
  __shared__ __align__(16) unsigned short lt[32][1024];   // 64 KB; castF unions first 12.8KB
  int bid = blockIdx.x;
  int grp = bid/5, r = bid - grp*5;
  int t = threadIdx.x;
  if(bid==0 && t==0) out[0] = 0.f;

  if(r < 4){
    // ---------- castF path, block index cb in [0,1024) ----------
    int cb = grp*4 + r;
    unsigned short* lds = &lt[0][0];                       // [64*68]
    float* gq = (float*)((char*)&lt[0][0] + 64*68*2);      // [16*64]
    int i0 = (cb & 127)*64, d0 = (cb >> 7)*64;
    int cx = t&15, ry = t>>4;
    float ca0=0.f,ca1=0.f,ca2=0.f,ca3=0.f;
    #pragma unroll
    for(int rr=0;rr<4;rr++){
      int row = rr*16 + ry;
      f32x4 fv = *(const f32x4*)&F[(size_t)(i0+row)*DD + d0 + cx*4];
      us4 u; u[0]=f2bf(fv[0]); u[1]=f2bf(fv[1]); u[2]=f2bf(fv[2]); u[3]=f2bf(fv[3]);
      *(us4*)&lds[row*68 + cx*4] = u;
      *(us4*)&Fb[(size_t)(i0+row)*DD + d0 + cx*4] = u;
      ca0+=fv[0]; ca1+=fv[1]; ca2+=fv[2]; ca3+=fv[3];
    }
    {
      f32x4 cv; cv[0]=ca0; cv[1]=ca1; cv[2]=ca2; cv[3]=ca3;
      *(f32x4*)&gq[ry*64 + cx*4] = cv;
    }
    __syncthreads();
    #pragma unroll
    for(int rr=0;rr<4;rr++){
      int d = rr*16 + ry;
      us4 u;
      #pragma unroll
      for(int q=0;q<4;q++) u[q] = lds[(cx*4+q)*68 + d];
      *(us4*)&FbT[(size_t)(d0+d)*NN + i0 + cx*4] = u;
    }
    __syncthreads();
    if(t<64){
      float s=0.f;
      #pragma unroll
      for(int j=0;j<16;j++) s += gq[j*64+t];
      gpart[(cb&127)*DD + d0 + t] = s;
    }
  } else {
    // ---------- softmaxT path, block index sb in [0,256), 32 rows each ----------
    int sb = grp;
    int l = t&63, w = t>>6;
    int i0 = sb*32;
    #pragma unroll
    for(int q=0;q<8;q++){
      int rr = w*8 + q;
      int row = i0 + rr;
      const float* lr = L + (size_t)row*CC;
      float v[16]; float mx = -1e30f;
      #pragma unroll
      for(int k=0;k<4;k++){
        int c4 = l*4 + 256*k;
        f32x4 fv;
        if(c4 < CC) fv = *(const f32x4*)&lr[c4];
        else { fv[0]=-1e30f; fv[1]=-1e30f; fv[2]=-1e30f; fv[3]=-1e30f; }
        v[4*k+0]=fv[0]; v[4*k+1]=fv[1]; v[4*k+2]=fv[2]; v[4*k+3]=fv[3];
        mx = fmaxf(mx, fmaxf(fmaxf(fv[0],fv[1]), fmaxf(fv[2],fv[3])));
      }
      mx = waveRedMax(mx);
      float s = 0.f;
      #pragma unroll
      for(int e=0;e<16;e++){ v[e] = __expf(v[e]-mx); s += v[e]; }
      s = waveRedSum(s);
      float inv = 1.0f/s;
      #pragma unroll
      for(int k=0;k<4;k++){
        int c4 = l*4 + 256*k;
        us4 u;
        #pragma unroll
        for(int j=0;j<4;j++){
          float p = v[4*k+j]*inv + 1e-8f;
          u[j] = (c4+j < CC)? f2bf(p) : (unsigned short)0;
        }
        *(us4*)&lt[rr][c4] = u;
      }
    }
    __syncthreads();
    // writeout: each lane writes 64B contiguous per c-row (full HBM granule)
    #pragma unroll
    for(int k=0;k<4;k++){
      int c = t + 256*k;
      #pragma unroll
      for(int h=0;h<4;h++){
        us8 a;
        #pragma unroll
        for(int j=0;j<8;j++) a[j] = lt[h*8+j][c];
        *(us8*)&PbT[(size_t)c*NN + i0 + h*8] = a;
      }
    }
  }
}

// ---- K2: GEMM1 (512 blocks, XCD-swizzled, split-K=16, dbuf, 8 waves)
//      each block also does a tiny distributed gred prefix (1 column of g).
__global__ __launch_bounds__(512,4) void k_gemm1(const unsigned short* __restrict__ A,  // PbT [1024][8192]
                                                 const unsigned short* __restrict__ B,  // FbT [512][8192]
                                                 unsigned short* __restrict__ Tpb,
                                                 const float* __restrict__ gpart,
                                                 float* __restrict__ g){
  __shared__ __align__(16) unsigned short smem[4*8192];   // A0 B0 A1 B1, 64 KB
  __shared__ float rs8[8];
  int bid = blockIdx.x;
  int t = threadIdx.x;
  // ---- gred prefix: this block reduces column d=bid of gpart (128 values) ----
  {
    float s = (t<128) ? gpart[(size_t)t*DD + bid] : 0.f;
    s = waveRedSum(s);
    if((t&63)==0) rs8[t>>6] = s;
    __syncthreads();
    if(t==0) g[bid] = rs8[0] + rs8[1];
  }
  int Lsw = (bid&7)*64 + (bid>>3);   // XCD-chunked bijective swizzle (512 = 8x64)
  int l = t&63, w = t>>6;            // 8 waves
  int bx = Lsw & 7, by = (Lsw>>3) & 3, bz = Lsw>>5;
  int m0 = bx*128, n0 = by*128;
  int k0 = bz*512;
  int wm = w>>1, wn = w&1;           // waves 4(M) x 2(N); per-wave 32x64
  f32x4 acc[2][4] = {};
  int srow = t>>3;                   // 0..63
  int scl  = (t&7) ^ (srow&7);       // pre-swizzled source chunk
  const unsigned short* Ab = A + (size_t)(m0 + srow)*NN + k0 + scl*8;
  const unsigned short* Bb = B + (size_t)(n0 + srow)*NN + k0 + scl*8;
  int ldsOff = w*512;                // 64 lanes x 8 elems per wave

  // prologue: stage tile 0 into buffer 0 (A rows srow, srow+64; same for B)
  #pragma unroll
  for(int q=0;q<2;q++){
    gload_lds16(Ab + (size_t)q*64*NN, smem + q*4096 + ldsOff);
    gload_lds16(Bb + (size_t)q*64*NN, smem + 8192 + q*4096 + ldsOff);
  }
  int cur = 0;
  for(int kt=0; kt<512; kt+=64){
    if(kt+64 < 512){
      unsigned short* base = smem + (cur^1)*16384;
      #pragma unroll
      for(int q=0;q<2;q++){
        gload_lds16(Ab + (size_t)q*64*NN + kt + 64, base + q*4096 + ldsOff);
        gload_lds16(Bb + (size_t)q*64*NN + kt + 64, base + 8192 + q*4096 + ldsOff);
      }
      asm volatile("s_waitcnt vmcnt(4)" ::: "memory");   // drain ONLY current tile
    } else {
      asm volatile("s_waitcnt vmcnt(0)" ::: "memory");
    }
    __builtin_amdgcn_s_barrier();                        // raw: no compiler vmcnt(0) drain
    const unsigned short* Ac = smem + cur*16384;
    const unsigned short* Bc = smem + cur*16384 + 8192;
    #pragma unroll
    for(int ks=0;ks<2;ks++){
      short8 af[2], bf[4];
      #pragma unroll
      for(int mi=0;mi<2;mi++){
        int rr = wm*32 + mi*16 + (l&15);
        int ch = ((ks<<2) + (l>>4)) ^ (rr&7);
        af[mi] = *(const short8*)&Ac[rr*64 + ch*8];
      }
      #pragma unroll
      for(int ni=0;ni<4;ni++){
        int rr = wn*64 + ni*16 + (l&15);
        int ch = ((ks<<2) + (l>>4)) ^ (rr&7);
        bf[ni] = *(const short8*)&Bc[rr*64 + ch*8];
      }
      #pragma unroll
      for(int mi=0;mi<2;mi++)
        #pragma unroll
        for(int ni=0;ni<4;ni++)
          acc[mi][ni] = __builtin_amdgcn_mfma_f32_16x16x32_bf16(af[mi], bf[ni], acc[mi][ni], 0,0,0);
    }
    __builtin_amdgcn_s_barrier();                        // reads done before next overwrite
    cur ^= 1;
  }
  unsigned short* Tz = Tpb + (size_t)bz*CPD;
  int rbase = (l>>4)*4;
  #pragma unroll
  for(int mi=0;mi<2;mi++){
    int c = m0 + wm*32 + mi*16 + rbase;
    #pragma unroll
    for(int ni=0;ni<4;ni++){
      int d = n0 + wn*64 + ni*16 + (l&15);
      #pragma unroll
      for(int j=0;j<4;j++)
        Tz[(size_t)(c+j)*DD + d] = f2bf(acc[mi][ni][j]);
    }
  }
}

// ---- K3: reduce 16 bf16 partials -> Ttb bf16 (phase 1) AND invr (phase 2); 512 blocks
__global__ __launch_bounds__(256) void k_redT(const unsigned short* __restrict__ Tpb,
                                              const unsigned short* __restrict__ Fb,
                                              const float* __restrict__ g,
                                              unsigned short* __restrict__ Ttb,
                                              float* __restrict__ invr){
  int t = threadIdx.x;
  size_t i = ((size_t)blockIdx.x*256 + (size_t)t)*4;   // 512*256*4 = CPD
  f32x4 s0 = {0.f,0.f,0.f,0.f};
  #pragma unroll
  for(int z=0;z<16;z++){
    us4 v = *(const us4*)&Tpb[(size_t)z*CPD + i];
    s0[0]+=bf2f(v[0]); s0[1]+=bf2f(v[1]); s0[2]+=bf2f(v[2]); s0[3]+=bf2f(v[3]);
  }
  us4 u;
  u[0]=f2bf(s0[0]); u[1]=f2bf(s0[1]); u[2]=f2bf(s0[2]); u[3]=f2bf(s0[3]);
  *(us4*)&Ttb[i] = u;
  // phase 2: invr for rows blockIdx.x*16 .. +15 (16 lanes per row x 32 d each)
  int row = blockIdx.x*16 + (t>>4);
  int seg = (t&15)*32;
  const unsigned short* fr = Fb + (size_t)row*DD + seg;
  const float* gr = g + seg;
  float s = 0.f;
  #pragma unroll
  for(int j=0;j<4;j++){
    us8 f8 = *(const us8*)&fr[j*8];
    f32x4 ga = *(const f32x4*)&gr[j*8];
    f32x4 gb = *(const f32x4*)&gr[j*8+4];
    s += bf2f(f8[0])*ga[0]+bf2f(f8[1])*ga[1]+bf2f(f8[2])*ga[2]+bf2f(f8[3])*ga[3]
       + bf2f(f8[4])*gb[0]+bf2f(f8[5])*gb[1]+bf2f(f8[6])*gb[2]+bf2f(f8[7])*gb[3];
  }
  s += __shfl_xor(s,1,64); s += __shfl_xor(s,2,64);
  s += __shfl_xor(s,4,64); s += __shfl_xor(s,8,64);
  if((t&15)==0) invr[row] = 1.0f/(s - 1.0f);
}

// ---- K4: GEMM2 (1D 512 blocks, XCD-swizzled, dbuf, 512 thr / 8 waves):
//      M = Fb x Ttb^T; KL epilogue from LDS-staged P^T tile; atomic finalize.
__global__ __launch_bounds__(512,4) void k_gemm2(const unsigned short* __restrict__ Fb,   // [8192][512]
                                                 const unsigned short* __restrict__ Bt,   // Ttb [1024][512]
                                                 const unsigned short* __restrict__ PbT,  // [1024][8192]
                                                 const float* __restrict__ invr,
                                                 float* __restrict__ out){
  __shared__ __align__(16) unsigned short smem[4*8192];   // A0 B0 A1 B1; epilogue P[128][136]
  __shared__ float red[8];
  int bid = blockIdx.x;
  int Lsw = (bid&7)*64 + (bid>>3);   // XCD-chunked bijective swizzle
  int t = threadIdx.x, l = t&63, w = t>>6;
  int m0 = (Lsw>>3)*128, n0 = (Lsw&7)*128;
  int wm = w>>1, wn = w&1;           // waves 4(M) x 2(N)
  f32x4 acc[2][4] = {};
  int srow = t>>3;
  int scl  = (t&7) ^ (srow&7);
  const unsigned short* Ab = Fb + (size_t)(m0 + srow)*DD + scl*8;
  const unsigned short* Bb = Bt + (size_t)(n0 + srow)*DD + scl*8;
  int ldsOff = w*512;

  // prologue: stage tile 0 into buffer 0
  #pragma unroll
  for(int q=0;q<2;q++){
    gload_lds16(Ab + (size_t)q*64*DD, smem + q*4096 + ldsOff);
    gload_lds16(Bb + (size_t)q*64*DD, smem + 8192 + q*4096 + ldsOff);
  }
  int cur = 0;
  for(int kt=0; kt<512; kt+=64){
    if(kt+64 < 512){
      unsigned short* base = smem + (cur^1)*16384;
      #pragma unroll
      for(int q=0;q<2;q++){
        gload_lds16(Ab + (size_t)q*64*DD + kt + 64, base + q*4096 + ldsOff);
        gload_lds16(Bb + (size_t)q*64*DD + kt + 64, base + 8192 + q*4096 + ldsOff);
      }
      asm volatile("s_waitcnt vmcnt(4)" ::: "memory");
    } else {
      asm volatile("s_waitcnt vmcnt(0)" ::: "memory");
    }
    __builtin_amdgcn_s_barrier();
    const unsigned short* Ac = smem + cur*16384;
    const unsigned short* Bc = smem + cur*16384 + 8192;
    #pragma unroll
    for(int ks=0;ks<2;ks++){
      short8 af[2], bf[4];
      #pragma unroll
      for(int mi=0;mi<2;mi++){
        int rr = wm*32 + mi*16 + (l&15);
        int ch = ((ks<<2) + (l>>4)) ^ (rr&7);
        af[mi] = *(const short8*)&Ac[rr*64 + ch*8];
      }
      #pragma unroll
      for(int ni=0;ni<4;ni++){
        int rr = wn*64 + ni*16 + (l&15);
        int ch = ((ks<<2) + (l>>4)) ^ (rr&7);
        bf[ni] = *(const short8*)&Bc[rr*64 + ch*8];
      }
      #pragma unroll
      for(int mi=0;mi<2;mi++)
        #pragma unroll
        for(int ni=0;ni<4;ni++)
          acc[mi][ni] = __builtin_amdgcn_mfma_f32_16x16x32_bf16(af[mi], bf[ni], acc[mi][ni], 0,0,0);
    }
    __builtin_amdgcn_s_barrier();
    cur ^= 1;
  }
  // stage P^T tile [c=n0..+127][i=m0..+127] into LDS, coalesced (row stride 136)
  __syncthreads();
  #pragma unroll
  for(int j=0;j<4;j++){
    int e = j*512 + t;
    int row = e >> 4;
    int ch  = e & 15;
    us8 v = *(const us8*)&PbT[(size_t)(n0+row)*NN + m0 + ch*8];
    *(us8*)&smem[row*136 + ch*8] = v;
  }
  __syncthreads();
  // KL epilogue from LDS (fast log: ws*log(ws/p) = ws*(__logf(ws)-__logf(p)))
  float kl = 0.f;
  int rbase = (l>>4)*4;
  #pragma unroll
  for(int mi=0;mi<2;mi++){
    int i_base = m0 + wm*32 + mi*16 + rbase;
    int ci = wm*32 + mi*16 + rbase;
    f32x4 ir4 = *(const f32x4*)&invr[i_base];
    #pragma unroll
    for(int ni=0;ni<4;ni++){
      int cr = wn*64 + ni*16 + (l&15);
      int c = n0 + cr;
      if(c < CC){
        us4 p4 = *(const us4*)&smem[cr*136 + ci];
        #pragma unroll
        for(int j=0;j<4;j++){
          float p = bf2f(p4[j]);
          float ws = (acc[mi][ni][j] - p) * ir4[j];
          kl += ws * (__logf(ws) - __logf(p));
        }
      }
    }
  }
  kl = waveRedSum(kl);
  if(l==0) red[w]=kl;
  __syncthreads();
  if(t==0){
    float s = red[0]+red[1]+red[2]+red[3]+red[4]+red[5]+red[6]+red[7];
    atomicAdd(out, s * (1.0f/(float)NN));
  }
}

extern "C" void kernel_launch(void* const* d_in, const int* in_sizes, int n_in,
                              void* d_out, int out_size, void* d_ws, size_t ws_size,
                              hipStream_t stream){
  const float* F = (const float*)d_in[0];   // [8192][512]
  const float* L = (const float*)d_in[1];   // [8192][1000]
  float* out = (float*)d_out;

  unsigned char* w8 = (unsigned char*)d_ws;
  unsigned short* FbT = (unsigned short*)w8;                   // 512*8192*2      = 8 MB
  unsigned short* PbT = (unsigned short*)(w8 + (8u<<20));      // 1024*8192*2     = 16 MB
  unsigned short* Tpb = (unsigned short*)(w8 + (24u<<20));     // 16*1024*512*2   = 16 MB
  unsigned short* Ttb = (unsigned short*)(w8 + (40u<<20));     // 1024*512*2      = 1 MB
  unsigned short* Fb  = (unsigned short*)(w8 + (41u<<20));     // 8192*512*2      = 8 MB
  float* gpart        = (float*)(w8 + (49u<<20));              // 128*512*4       = 256 KB
  float* g            = (float*)(w8 + (49u<<20) + 262144);     // 512*4
  float* invr         = (float*)(w8 + (49u<<20) + 264192);     // 8192*4

  hipLaunchKernelGGL(k_prep,  dim3(1280), dim3(256), 0, stream, F, L, FbT, Fb, gpart, PbT, out);
  hipLaunchKernelGGL(k_gemm1, dim3(512),  dim3(512), 0, stream, PbT, FbT, Tpb, gpart, g);
  hipLaunchKernelGGL(k_redT,  dim3(512),  dim3(256), 0, stream, Tpb, Fb, g, Ttb, invr);
  hipLaunchKernelGGL(k_gemm2, dim3(512),  dim3(512), 0, stream, Fb, Ttb, PbT, invr, out);
}

// Round 18
// 65.010 us; speedup vs baseline: 1.0620x; 1.0620x over previous
//
#include <hip/hip_runtime.h>
#include <math.h>

#define NN 8192
#define DD 512
#define CC 1000
#define CP 1024   // padded C
#define CPD (CP*DD)

typedef __attribute__((ext_vector_type(8))) short short8;     // bf16x8 MFMA frag
typedef __attribute__((ext_vector_type(4))) float f32x4;
typedef __attribute__((ext_vector_type(4))) unsigned short us4;
typedef __attribute__((ext_vector_type(8))) unsigned short us8;

__device__ __forceinline__ float bf2f(unsigned short u){
  union{unsigned int i; float f;} v; v.i = ((unsigned int)u)<<16; return v.f;
}
__device__ __forceinline__ unsigned short f2bf(float f){
  union{float f; unsigned int i;} v; v.f = f;
  unsigned int r = v.i + 0x7FFF + ((v.i>>16)&1);   // RNE
  return (unsigned short)(r>>16);
}
__device__ __forceinline__ float waveRedSum(float v){
  #pragma unroll
  for(int o=32;o;o>>=1) v += __shfl_xor(v,o,64);
  return v;
}
__device__ __forceinline__ float waveRedMax(float v){
  #pragma unroll
  for(int o=32;o;o>>=1) v = fmaxf(v,__shfl_xor(v,o,64));
  return v;
}
__device__ __forceinline__ void gload_lds16(const void* g, void* l){
  __builtin_amdgcn_global_load_lds((const __attribute__((address_space(1))) void*)g,
                                   (__attribute__((address_space(3))) void*)l, 16, 0, 0);
}

// ---- K1: merged prep. Blocks interleaved 2 castF : 1 softmaxT (512 groups of 3).
//      Also zeroes out[0] (block 0) for gemm2's atomic finalize.
__global__ __launch_bounds__(256) void k_prep(const float* __restrict__ F,
                                              const float* __restrict__ L,
                                              unsigned short* __restrict__ FbT,
                                              unsigned short* __restrict__ Fb,
                                              float* __restrict__ gpart,
                                              unsigned short* __restrict__ PbT,
                                              float* __restrict__ out){
  __shared__ __align__(16) char smem[16*1032*2];   // 33 KB union
  int bid = blockIdx.x;
  int grp = bid/3, r = bid - grp*3;
  int t = threadIdx.x;
  if(bid==0 && t==0) out[0] = 0.f;

  if(r < 2){
    // ---------- castF path, block index cb in [0,1024) ----------
    int cb = grp*2 + r;
    unsigned short* lds = (unsigned short*)smem;           // [64*68]
    float* gq = (float*)(smem + 64*68*2);                  // [16*64]
    int i0 = (cb & 127)*64, d0 = (cb >> 7)*64;
    int cx = t&15, ry = t>>4;
    float ca0=0.f,ca1=0.f,ca2=0.f,ca3=0.f;
    #pragma unroll
    for(int rr=0;rr<4;rr++){
      int row = rr*16 + ry;
      f32x4 fv = *(const f32x4*)&F[(size_t)(i0+row)*DD + d0 + cx*4];
      us4 u; u[0]=f2bf(fv[0]); u[1]=f2bf(fv[1]); u[2]=f2bf(fv[2]); u[3]=f2bf(fv[3]);
      *(us4*)&lds[row*68 + cx*4] = u;
      *(us4*)&Fb[(size_t)(i0+row)*DD + d0 + cx*4] = u;
      ca0+=fv[0]; ca1+=fv[1]; ca2+=fv[2]; ca3+=fv[3];
    }
    {
      f32x4 cv; cv[0]=ca0; cv[1]=ca1; cv[2]=ca2; cv[3]=ca3;
      *(f32x4*)&gq[ry*64 + cx*4] = cv;
    }
    __syncthreads();
    #pragma unroll
    for(int rr=0;rr<4;rr++){
      int d = rr*16 + ry;
      us4 u;
      #pragma unroll
      for(int q=0;q<4;q++) u[q] = lds[(cx*4+q)*68 + d];
      *(us4*)&FbT[(size_t)(d0+d)*NN + i0 + cx*4] = u;
    }
    __syncthreads();
    if(t<64){
      float s=0.f;
      #pragma unroll
      for(int j=0;j<16;j++) s += gq[j*64+t];
      gpart[(cb&127)*DD + d0 + t] = s;
    }
  } else {
    // ---------- softmaxT path, block index sb in [0,512) ----------
    int sb = grp;
    unsigned short (*lt)[1032] = (unsigned short(*)[1032])smem;   // [16][1032]
    int l = t&63, w = t>>6;
    int i0 = sb*16;
    #pragma unroll
    for(int q=0;q<4;q++){
      int rr = w*4 + q;
      int row = i0 + rr;
      const float* lr = L + (size_t)row*CC;
      float v[16]; float mx = -1e30f;
      #pragma unroll
      for(int k=0;k<4;k++){
        int c4 = l*4 + 256*k;
        f32x4 fv;
        if(c4 < CC) fv = *(const f32x4*)&lr[c4];
        else { fv[0]=-1e30f; fv[1]=-1e30f; fv[2]=-1e30f; fv[3]=-1e30f; }
        v[4*k+0]=fv[0]; v[4*k+1]=fv[1]; v[4*k+2]=fv[2]; v[4*k+3]=fv[3];
        mx = fmaxf(mx, fmaxf(fmaxf(fv[0],fv[1]), fmaxf(fv[2],fv[3])));
      }
      mx = waveRedMax(mx);
      float s = 0.f;
      #pragma unroll
      for(int e=0;e<16;e++){ v[e] = __expf(v[e]-mx); s += v[e]; }
      s = waveRedSum(s);
      float inv = 1.0f/s;
      #pragma unroll
      for(int k=0;k<4;k++){
        int c4 = l*4 + 256*k;
        us4 u;
        #pragma unroll
        for(int j=0;j<4;j++){
          float p = v[4*k+j]*inv + 1e-8f;
          u[j] = (c4+j < CC)? f2bf(p) : (unsigned short)0;
        }
        *(us4*)&lt[rr][c4] = u;
      }
    }
    __syncthreads();
    #pragma unroll
    for(int k=0;k<4;k++){
      int c = t + 256*k;
      us8 a, b;
      #pragma unroll
      for(int j=0;j<8;j++){ a[j] = lt[j][c]; b[j] = lt[j+8][c]; }
      *(us8*)&PbT[(size_t)c*NN + i0]     = a;
      *(us8*)&PbT[(size_t)c*NN + i0 + 8] = b;
    }
  }
}

// ---- K2: gred (blocks 0..7) + GEMM1 (blocks 8..519, XCD-swizzled, split-K=16, dbuf)
//      512 threads / 8 waves per block -> 16 waves/CU for latency hiding.
__global__ __launch_bounds__(512,4) void k_gemm1(const unsigned short* __restrict__ A,  // PbT [1024][8192]
                                                 const unsigned short* __restrict__ B,  // FbT [512][8192]
                                                 unsigned short* __restrict__ Tpb,
                                                 const float* __restrict__ gpart,
                                                 float* __restrict__ g){
  __shared__ __align__(16) unsigned short smem[4*8192];   // A0 B0 A1 B1, 64 KB
  __shared__ float rs[8][64];
  int bid = blockIdx.x;
  int t = threadIdx.x;
  if(bid < 8){
    int d = bid*64 + (t&63);
    int q = t>>6;
    float s = 0.f;
    #pragma unroll
    for(int j=0;j<16;j++) s += gpart[(size_t)(q*16+j)*DD + d];
    rs[q][t&63] = s;
    __syncthreads();
    if(q==0){
      float r2 = 0.f;
      #pragma unroll
      for(int j=0;j<8;j++) r2 += rs[j][t&63];
      g[d] = r2;
    }
    return;
  }
  int gb = bid - 8;
  int Lsw = (gb&7)*64 + (gb>>3);     // XCD-chunked bijective swizzle (512 = 8x64)
  int l = t&63, w = t>>6;            // 8 waves
  int bx = Lsw & 7, by = (Lsw>>3) & 3, bz = Lsw>>5;
  int m0 = bx*128, n0 = by*128;
  int k0 = bz*512;
  int wm = w>>1, wn = w&1;           // waves 4(M) x 2(N); per-wave 32x64
  f32x4 acc[2][4] = {};
  int srow = t>>3;                   // 0..63
  int scl  = (t&7) ^ (srow&7);       // pre-swizzled source chunk
  const unsigned short* Ab = A + (size_t)(m0 + srow)*NN + k0 + scl*8;
  const unsigned short* Bb = B + (size_t)(n0 + srow)*NN + k0 + scl*8;
  int ldsOff = w*512;                // 64 lanes x 8 elems per wave

  // prologue: stage tile 0 into buffer 0 (A rows srow, srow+64; same for B)
  #pragma unroll
  for(int q=0;q<2;q++){
    gload_lds16(Ab + (size_t)q*64*NN, smem + q*4096 + ldsOff);
    gload_lds16(Bb + (size_t)q*64*NN, smem + 8192 + q*4096 + ldsOff);
  }
  int cur = 0;
  for(int kt=0; kt<512; kt+=64){
    if(kt+64 < 512){
      unsigned short* base = smem + (cur^1)*16384;
      #pragma unroll
      for(int q=0;q<2;q++){
        gload_lds16(Ab + (size_t)q*64*NN + kt + 64, base + q*4096 + ldsOff);
        gload_lds16(Bb + (size_t)q*64*NN + kt + 64, base + 8192 + q*4096 + ldsOff);
      }
      asm volatile("s_waitcnt vmcnt(4)" ::: "memory");   // drain ONLY current tile
    } else {
      asm volatile("s_waitcnt vmcnt(0)" ::: "memory");
    }
    __builtin_amdgcn_s_barrier();                        // raw: no compiler vmcnt(0) drain
    const unsigned short* Ac = smem + cur*16384;
    const unsigned short* Bc = smem + cur*16384 + 8192;
    #pragma unroll
    for(int ks=0;ks<2;ks++){
      short8 af[2], bf[4];
      #pragma unroll
      for(int mi=0;mi<2;mi++){
        int rr = wm*32 + mi*16 + (l&15);
        int ch = ((ks<<2) + (l>>4)) ^ (rr&7);
        af[mi] = *(const short8*)&Ac[rr*64 + ch*8];
      }
      #pragma unroll
      for(int ni=0;ni<4;ni++){
        int rr = wn*64 + ni*16 + (l&15);
        int ch = ((ks<<2) + (l>>4)) ^ (rr&7);
        bf[ni] = *(const short8*)&Bc[rr*64 + ch*8];
      }
      #pragma unroll
      for(int mi=0;mi<2;mi++)
        #pragma unroll
        for(int ni=0;ni<4;ni++)
          acc[mi][ni] = __builtin_amdgcn_mfma_f32_16x16x32_bf16(af[mi], bf[ni], acc[mi][ni], 0,0,0);
    }
    __builtin_amdgcn_s_barrier();                        // reads done before next overwrite
    cur ^= 1;
  }
  unsigned short* Tz = Tpb + (size_t)bz*CPD;
  int rbase = (l>>4)*4;
  #pragma unroll
  for(int mi=0;mi<2;mi++){
    int c = m0 + wm*32 + mi*16 + rbase;
    #pragma unroll
    for(int ni=0;ni<4;ni++){
      int d = n0 + wn*64 + ni*16 + (l&15);
      #pragma unroll
      for(int j=0;j<4;j++)
        Tz[(size_t)(c+j)*DD + d] = f2bf(acc[mi][ni][j]);
    }
  }
}

// ---- K3: reduce 16 bf16 partials -> Ttb bf16 (phase 1) AND invr (phase 2); 512 blocks
__global__ __launch_bounds__(256) void k_redT(const unsigned short* __restrict__ Tpb,
                                              const unsigned short* __restrict__ Fb,
                                              const float* __restrict__ g,
                                              unsigned short* __restrict__ Ttb,
                                              float* __restrict__ invr){
  int t = threadIdx.x;
  size_t i = ((size_t)blockIdx.x*256 + (size_t)t)*4;   // 512*256*4 = CPD
  f32x4 s0 = {0.f,0.f,0.f,0.f};
  #pragma unroll
  for(int z=0;z<16;z++){
    us4 v = *(const us4*)&Tpb[(size_t)z*CPD + i];
    s0[0]+=bf2f(v[0]); s0[1]+=bf2f(v[1]); s0[2]+=bf2f(v[2]); s0[3]+=bf2f(v[3]);
  }
  us4 u;
  u[0]=f2bf(s0[0]); u[1]=f2bf(s0[1]); u[2]=f2bf(s0[2]); u[3]=f2bf(s0[3]);
  *(us4*)&Ttb[i] = u;
  // phase 2: invr for rows blockIdx.x*16 .. +15 (16 lanes per row x 32 d each)
  int row = blockIdx.x*16 + (t>>4);
  int seg = (t&15)*32;
  const unsigned short* fr = Fb + (size_t)row*DD + seg;
  const float* gr = g + seg;
  float s = 0.f;
  #pragma unroll
  for(int j=0;j<4;j++){
    us8 f8 = *(const us8*)&fr[j*8];
    f32x4 ga = *(const f32x4*)&gr[j*8];
    f32x4 gb = *(const f32x4*)&gr[j*8+4];
    s += bf2f(f8[0])*ga[0]+bf2f(f8[1])*ga[1]+bf2f(f8[2])*ga[2]+bf2f(f8[3])*ga[3]
       + bf2f(f8[4])*gb[0]+bf2f(f8[5])*gb[1]+bf2f(f8[6])*gb[2]+bf2f(f8[7])*gb[3];
  }
  s += __shfl_xor(s,1,64); s += __shfl_xor(s,2,64);
  s += __shfl_xor(s,4,64); s += __shfl_xor(s,8,64);
  if((t&15)==0) invr[row] = 1.0f/(s - 1.0f);
}

// ---- K4: GEMM2 (1D 512 blocks, XCD-swizzled, dbuf, 512 thr / 8 waves):
//      M = Fb x Ttb^T; KL epilogue from LDS-staged P^T tile; atomic finalize.
__global__ __launch_bounds__(512,4) void k_gemm2(const unsigned short* __restrict__ Fb,   // [8192][512]
                                                 const unsigned short* __restrict__ Bt,   // Ttb [1024][512]
                                                 const unsigned short* __restrict__ PbT,  // [1024][8192]
                                                 const float* __restrict__ invr,
                                                 float* __restrict__ out){
  __shared__ __align__(16) unsigned short smem[4*8192];   // A0 B0 A1 B1; epilogue P[128][136]
  __shared__ float red[8];
  int bid = blockIdx.x;
  int Lsw = (bid&7)*64 + (bid>>3);   // XCD-chunked bijective swizzle
  int t = threadIdx.x, l = t&63, w = t>>6;
  int m0 = (Lsw>>3)*128, n0 = (Lsw&7)*128;
  int wm = w>>1, wn = w&1;           // waves 4(M) x 2(N)
  f32x4 acc[2][4] = {};
  int srow = t>>3;
  int scl  = (t&7) ^ (srow&7);
  const unsigned short* Ab = Fb + (size_t)(m0 + srow)*DD + scl*8;
  const unsigned short* Bb = Bt + (size_t)(n0 + srow)*DD + scl*8;
  int ldsOff = w*512;

  // prologue: stage tile 0 into buffer 0
  #pragma unroll
  for(int q=0;q<2;q++){
    gload_lds16(Ab + (size_t)q*64*DD, smem + q*4096 + ldsOff);
    gload_lds16(Bb + (size_t)q*64*DD, smem + 8192 + q*4096 + ldsOff);
  }
  int cur = 0;
  for(int kt=0; kt<512; kt+=64){
    if(kt+64 < 512){
      unsigned short* base = smem + (cur^1)*16384;
      #pragma unroll
      for(int q=0;q<2;q++){
        gload_lds16(Ab + (size_t)q*64*DD + kt + 64, base + q*4096 + ldsOff);
        gload_lds16(Bb + (size_t)q*64*DD + kt + 64, base + 8192 + q*4096 + ldsOff);
      }
      asm volatile("s_waitcnt vmcnt(4)" ::: "memory");
    } else {
      asm volatile("s_waitcnt vmcnt(0)" ::: "memory");
    }
    __builtin_amdgcn_s_barrier();
    const unsigned short* Ac = smem + cur*16384;
    const unsigned short* Bc = smem + cur*16384 + 8192;
    #pragma unroll
    for(int ks=0;ks<2;ks++){
      short8 af[2], bf[4];
      #pragma unroll
      for(int mi=0;mi<2;mi++){
        int rr = wm*32 + mi*16 + (l&15);
        int ch = ((ks<<2) + (l>>4)) ^ (rr&7);
        af[mi] = *(const short8*)&Ac[rr*64 + ch*8];
      }
      #pragma unroll
      for(int ni=0;ni<4;ni++){
        int rr = wn*64 + ni*16 + (l&15);
        int ch = ((ks<<2) + (l>>4)) ^ (rr&7);
        bf[ni] = *(const short8*)&Bc[rr*64 + ch*8];
      }
      #pragma unroll
      for(int mi=0;mi<2;mi++)
        #pragma unroll
        for(int ni=0;ni<4;ni++)
          acc[mi][ni] = __builtin_amdgcn_mfma_f32_16x16x32_bf16(af[mi], bf[ni], acc[mi][ni], 0,0,0);
    }
    __builtin_amdgcn_s_barrier();
    cur ^= 1;
  }
  // stage P^T tile [c=n0..+127][i=m0..+127] into LDS, coalesced (row stride 136)
  __syncthreads();
  #pragma unroll
  for(int j=0;j<4;j++){
    int e = j*512 + t;
    int row = e >> 4;
    int ch  = e & 15;
    us8 v = *(const us8*)&PbT[(size_t)(n0+row)*NN + m0 + ch*8];
    *(us8*)&smem[row*136 + ch*8] = v;
  }
  __syncthreads();
  // KL epilogue from LDS (fast log: ws*log(ws/p) = ws*(__logf(ws)-__logf(p)))
  float kl = 0.f;
  int rbase = (l>>4)*4;
  #pragma unroll
  for(int mi=0;mi<2;mi++){
    int i_base = m0 + wm*32 + mi*16 + rbase;
    int ci = wm*32 + mi*16 + rbase;
    f32x4 ir4 = *(const f32x4*)&invr[i_base];
    #pragma unroll
    for(int ni=0;ni<4;ni++){
      int cr = wn*64 + ni*16 + (l&15);
      int c = n0 + cr;
      if(c < CC){
        us4 p4 = *(const us4*)&smem[cr*136 + ci];
        #pragma unroll
        for(int j=0;j<4;j++){
          float p = bf2f(p4[j]);
          float ws = (acc[mi][ni][j] - p) * ir4[j];
          kl += ws * (__logf(ws) - __logf(p));
        }
      }
    }
  }
  kl = waveRedSum(kl);
  if(l==0) red[w]=kl;
  __syncthreads();
  if(t==0){
    float s = red[0]+red[1]+red[2]+red[3]+red[4]+red[5]+red[6]+red[7];
    atomicAdd(out, s * (1.0f/(float)NN));
  }
}

extern "C" void kernel_launch(void* const* d_in, const int* in_sizes, int n_in,
                              void* d_out, int out_size, void* d_ws, size_t ws_size,
                              hipStream_t stream){
  const float* F = (const float*)d_in[0];   // [8192][512]
  const float* L = (const float*)d_in[1];   // [8192][1000]
  float* out = (float*)d_out;

  unsigned char* w8 = (unsigned char*)d_ws;
  unsigned short* FbT = (unsigned short*)w8;                   // 512*8192*2      = 8 MB
  unsigned short* PbT = (unsigned short*)(w8 + (8u<<20));      // 1024*8192*2     = 16 MB
  unsigned short* Tpb = (unsigned short*)(w8 + (24u<<20));     // 16*1024*512*2   = 16 MB
  unsigned short* Ttb = (unsigned short*)(w8 + (40u<<20));     // 1024*512*2      = 1 MB
  unsigned short* Fb  = (unsigned short*)(w8 + (41u<<20));     // 8192*512*2      = 8 MB
  float* gpart        = (float*)(w8 + (49u<<20));              // 128*512*4       = 256 KB
  float* g            = (float*)(w8 + (49u<<20) + 262144);     // 512*4
  float* invr         = (float*)(w8 + (49u<<20) + 264192);     // 8192*4

  hipLaunchKernelGGL(k_prep,  dim3(1536), dim3(256), 0, stream, F, L, FbT, Fb, gpart, PbT, out);
  hipLaunchKernelGGL(k_gemm1, dim3(520),  dim3(512), 0, stream, PbT, FbT, Tpb, gpart, g);
  hipLaunchKernelGGL(k_redT,  dim3(512),  dim3(256), 0, stream, Tpb, Fb, g, Ttb, invr);
  hipLaunchKernelGGL(k_gemm2, dim3(512),  dim3(512), 0, stream, Fb, Ttb, PbT, invr, out);
}